// Round 1
// baseline (453.165 us; speedup 1.0000x reference)
//
#include <hip/hip_runtime.h>

// LengthRegulator: x (32,1024,384) f32, duration (32,1024) i32, max_mel_len=8192
// out0: (32, 8192, 384) f32 gathered+masked;  out1: mel_len (32,) written as f32
// (harness reads the concatenated flat output buffer as float32 elements).

#define BATCH 32
#define SRC_S 1024
#define DIM   384
#define ROWS  32          // output rows per block in gather kernel
#define C4    (DIM / 4)   // 96 float4 per row

// One block per batch, SRC_S threads: inclusive scan (Hillis-Steele in LDS).
__global__ void lr_cumsum_kernel(const int* __restrict__ duration,
                                 int* __restrict__ csum,
                                 float* __restrict__ mel_out) {
    __shared__ int s[SRC_S];
    const int b = blockIdx.x;
    const int tid = threadIdx.x;
    s[tid] = duration[b * SRC_S + tid];
    for (int off = 1; off < SRC_S; off <<= 1) {
        __syncthreads();
        const int add = (tid >= off) ? s[tid - off] : 0;
        __syncthreads();
        s[tid] += add;
    }
    __syncthreads();
    csum[b * SRC_S + tid] = s[tid];
    if (tid == SRC_S - 1) {
        mel_out[b] = (float)s[SRC_S - 1];   // mel_len, exactly representable
    }
}

// Grid (T/ROWS, BATCH), 256 threads. LDS-resident csum, 32 binary searches,
// then 32 rows x 96 float4 coalesced gather+store.
__global__ void lr_gather_kernel(const float* __restrict__ x,
                                 const int* __restrict__ csum,
                                 float* __restrict__ out, int T) {
    __shared__ int c[SRC_S];
    __shared__ int src[ROWS];   // source row idx, or -1 => write zeros
    const int b = blockIdx.y;
    const int t0 = blockIdx.x * ROWS;
    const int tid = threadIdx.x;

    // Stage csum[b, :] into LDS: 1024 ints = 256 x int4, coalesced.
    ((int4*)c)[tid] = ((const int4*)(csum + b * SRC_S))[tid];
    __syncthreads();

    const int mel_len = c[SRC_S - 1];
    if (tid < ROWS) {
        const int t = t0 + tid;
        // upper_bound: count of csum entries <= t  (searchsorted side='right')
        int lo = 0, hi = SRC_S;
        while (lo < hi) {
            const int mid = (lo + hi) >> 1;
            if (c[mid] <= t) lo = mid + 1; else hi = mid;
        }
        const int idx = (lo < SRC_S - 1) ? lo : (SRC_S - 1);  // clip
        src[tid] = (t < mel_len && t < T) ? idx : ((t < T) ? -1 : -2);
    }
    __syncthreads();

    float4* __restrict__ out4 = (float4*)(out + ((size_t)b * T + t0) * DIM);
    const float4* __restrict__ x4 = (const float4*)(x + (size_t)b * SRC_S * DIM);

    #pragma unroll
    for (int i = tid; i < ROWS * C4; i += 256) {
        const int row = i / C4;          // const-divide -> magic multiply
        const int col = i - row * C4;
        const int sidx = src[row];
        if (sidx == -2) continue;        // row beyond T (never happens at T=8192)
        float4 v = make_float4(0.f, 0.f, 0.f, 0.f);
        if (sidx >= 0) v = x4[(size_t)sidx * C4 + col];
        out4[(size_t)row * C4 + col] = v;
    }
}

extern "C" void kernel_launch(void* const* d_in, const int* in_sizes, int n_in,
                              void* d_out, int out_size, void* d_ws, size_t ws_size,
                              hipStream_t stream) {
    const float* x = (const float*)d_in[0];
    const int* duration = (const int*)d_in[1];
    // max_mel_len is a device scalar; derive T from out_size instead:
    // out_size = BATCH*T*DIM + BATCH
    const int T = (out_size - BATCH) / (BATCH * DIM);   // 8192

    int* csum = (int*)d_ws;                             // BATCH*SRC_S ints
    float* out = (float*)d_out;
    float* mel_out = out + (size_t)BATCH * T * DIM;     // out1 region

    lr_cumsum_kernel<<<BATCH, SRC_S, 0, stream>>>(duration, csum, mel_out);

    dim3 grid((T + ROWS - 1) / ROWS, BATCH);
    lr_gather_kernel<<<grid, 256, 0, stream>>>(x, csum, out, T);
}

// Round 3
// 446.263 us; speedup vs baseline: 1.0155x; 1.0155x over previous
//
#include <hip/hip_runtime.h>

// LengthRegulator: x (32,1024,384) f32, duration (32,1024) i32, max_mel_len=8192
// out0: (32, 8192, 384) f32 gathered+masked;  out1: mel_len (32,) as f32.
//
// Structure:
//  Phase 1 (32 blocks x 1024 thr): LDS scan of duration -> run-expansion
//    scatter writes idx[b,t] (source row for each output row; -1 => zero row),
//    tail [mel_len, T) gets -1. Writes are sorted & dense: ~coalesced. 1 MB ws.
//  Phase 2 (256x32 blocks x 256 thr): pure streaming gather. No LDS, no
//    barriers, no search. 1 idx int per row (L1 broadcast), 16B gather
//    loads (x is 1.5 MB/batch -> L2-resident), non-temporal 16B stores.

#define BATCH 32
#define SRC_S 1024
#define DIM   384
#define ROWS  32          // output rows per gather block
#define C4    (DIM / 4)   // 96 16B-vectors per row

typedef float f32x4 __attribute__((ext_vector_type(4)));   // clang vector: OK
                                                           // for nontemporal builtins

__global__ void lr_scan_idx_kernel(const int* __restrict__ duration,
                                   int* __restrict__ idx_g,
                                   float* __restrict__ mel_out, int T) {
    __shared__ int s[SRC_S];
    const int b = blockIdx.x;
    const int tid = threadIdx.x;
    const int d = duration[b * SRC_S + tid];
    s[tid] = d;
    for (int off = 1; off < SRC_S; off <<= 1) {
        __syncthreads();
        const int add = (tid >= off) ? s[tid - off] : 0;
        __syncthreads();
        s[tid] += add;
    }
    __syncthreads();
    const int end = s[tid];          // inclusive csum
    const int start = end - d;       // exclusive csum
    const int mel_len = s[SRC_S - 1];

    int* __restrict__ ib = idx_g + (size_t)b * T;
    // run-expansion: output rows [start, end) come from source row `tid`.
    for (int t = start; t < end; ++t) ib[t] = tid;
    // tail sentinel: rows >= mel_len are masked to zero.
    for (int t = mel_len + tid; t < T; t += SRC_S) ib[t] = -1;

    if (tid == SRC_S - 1) mel_out[b] = (float)mel_len;  // exactly representable
}

__global__ __launch_bounds__(256)
void lr_gather_kernel(const f32x4* __restrict__ x4,
                      const int* __restrict__ idx_g,
                      f32x4* __restrict__ out4, int T) {
    const int b = blockIdx.y;
    const int t0 = blockIdx.x * ROWS;
    const int tid = threadIdx.x;

    const int* __restrict__ ib = idx_g + (size_t)b * T + t0;
    const f32x4* __restrict__ xb = x4 + (size_t)b * SRC_S * C4;
    f32x4* __restrict__ ob = out4 + ((size_t)b * T + t0) * C4;

    #pragma unroll
    for (int k = 0; k < (ROWS * C4) / 256; ++k) {   // 12 iterations
        const int i = tid + k * 256;
        const int row = i / C4;                      // const-div -> magic mul
        const int col = i - row * C4;
        const int sidx = ib[row];                    // 8 lanes share -> broadcast
        f32x4 v = (f32x4)(0.f);
        if (sidx >= 0) v = xb[(size_t)sidx * C4 + col];
        __builtin_nontemporal_store(v, &ob[i]);      // streaming out
    }
}

extern "C" void kernel_launch(void* const* d_in, const int* in_sizes, int n_in,
                              void* d_out, int out_size, void* d_ws, size_t ws_size,
                              hipStream_t stream) {
    const float* x = (const float*)d_in[0];
    const int* duration = (const int*)d_in[1];
    const int T = (out_size - BATCH) / (BATCH * DIM);   // 8192

    int* idx_g = (int*)d_ws;                            // BATCH*T ints = 1 MB
    float* out = (float*)d_out;
    float* mel_out = out + (size_t)BATCH * T * DIM;     // out1 region

    lr_scan_idx_kernel<<<BATCH, SRC_S, 0, stream>>>(duration, idx_g, mel_out, T);

    dim3 grid((T + ROWS - 1) / ROWS, BATCH);
    lr_gather_kernel<<<grid, 256, 0, stream>>>((const f32x4*)x, idx_g,
                                               (f32x4*)out, T);
}

// Round 4
// 438.670 us; speedup vs baseline: 1.0330x; 1.0173x over previous
//
#include <hip/hip_runtime.h>

// LengthRegulator: x (32,1024,384) f32, duration (32,1024) i32, max_mel_len=8192
// out0: (32, 8192, 384) f32 gathered+masked;  out1: mel_len (32,) as f32.
//
//  Phase 1 (32 blocks x 1024 thr): shuffle-based scan (2 barriers) ->
//    run-expansion scatter writes idx[b,t]; tail [mel_len,T) = -1. idx stays
//    L2-resident (normal stores) for phase 2.
//  Phase 2 (8192 blocks x 256 thr, XCD-swizzled): streaming gather. No LDS,
//    no barriers. 16B gather loads (4 batches/XCD -> ~L2-resident),
//    non-temporal 16B output stores.

#define BATCH 32
#define SRC_S 1024
#define DIM   384
#define ROWS  32          // output rows per gather block
#define C4    (DIM / 4)   // 96 16B-vectors per row
#define NXCD  8

typedef float f32x4 __attribute__((ext_vector_type(4)));

__global__ void lr_scan_idx_kernel(const int* __restrict__ duration,
                                   int* __restrict__ idx_g,
                                   float* __restrict__ mel_out, int T) {
    __shared__ int wsum[16];
    const int b = blockIdx.x;
    const int tid = threadIdx.x;
    const int lane = tid & 63;
    const int wid = tid >> 6;          // 16 waves
    const int d = duration[b * SRC_S + tid];

    // wave-level inclusive scan, no barriers
    int v = d;
    #pragma unroll
    for (int off = 1; off < 64; off <<= 1) {
        const int n = __shfl_up(v, off, 64);
        if (lane >= off) v += n;
    }
    if (lane == 63) wsum[wid] = v;
    __syncthreads();
    if (tid < 16) {                    // scan the 16 wave totals (lanes 0..15)
        int w = wsum[tid];
        #pragma unroll
        for (int off = 1; off < 16; off <<= 1) {
            const int n = __shfl_up(w, off, 64);
            if (tid >= off) w += n;
        }
        wsum[tid] = w;
    }
    __syncthreads();
    const int wbase = (wid == 0) ? 0 : wsum[wid - 1];
    const int end = wbase + v;         // inclusive csum
    const int start = end - d;         // exclusive csum
    const int mel_len = wsum[15];

    int* __restrict__ ib = idx_g + (size_t)b * T;
    for (int t = start; t < end; ++t) ib[t] = tid;        // run-expansion
    for (int t = mel_len + tid; t < T; t += SRC_S) ib[t] = -1;  // masked tail

    if (tid == SRC_S - 1) mel_out[b] = (float)mel_len;    // exactly representable
}

__global__ __launch_bounds__(256)
void lr_gather_kernel(const f32x4* __restrict__ x4,
                      const int* __restrict__ idx_g,
                      f32x4* __restrict__ out4, int T) {
    // XCD-aware swizzle: consecutive blocks go to XCD l%8 (heuristic only).
    // Give each XCD 4 whole batches -> per-XCD x working set 4x1.5MB ~ L2.
    const int l = blockIdx.x;              // 0 .. 8191
    const int xcd = l & (NXCD - 1);
    const int j = l >> 3;                  // 0 .. 1023
    const int b = xcd + NXCD * (j >> 8);   // 4 batches per XCD slot
    const int t0 = (j & 255) * ROWS;
    const int tid = threadIdx.x;

    const int* __restrict__ ib = idx_g + (size_t)b * T + t0;
    const f32x4* __restrict__ xb = x4 + (size_t)b * SRC_S * C4;
    f32x4* __restrict__ ob = out4 + ((size_t)b * T + t0) * C4;

    #pragma unroll
    for (int k = 0; k < (ROWS * C4) / 256; ++k) {   // 12 iterations
        const int i = tid + k * 256;
        const int row = i / C4;                      // const-div -> magic mul
        const int col = i - row * C4;
        const int sidx = ib[row];
        f32x4 v = (f32x4)(0.f);
        if (sidx >= 0) v = xb[(size_t)sidx * C4 + col];
        __builtin_nontemporal_store(v, &ob[i]);      // streaming out
    }
}

extern "C" void kernel_launch(void* const* d_in, const int* in_sizes, int n_in,
                              void* d_out, int out_size, void* d_ws, size_t ws_size,
                              hipStream_t stream) {
    const float* x = (const float*)d_in[0];
    const int* duration = (const int*)d_in[1];
    const int T = (out_size - BATCH) / (BATCH * DIM);   // 8192

    int* idx_g = (int*)d_ws;                            // BATCH*T ints = 1 MB
    float* out = (float*)d_out;
    float* mel_out = out + (size_t)BATCH * T * DIM;     // out1 region

    lr_scan_idx_kernel<<<BATCH, SRC_S, 0, stream>>>(duration, idx_g, mel_out, T);

    const int nblocks = BATCH * (T / ROWS);             // 8192, 1D swizzled grid
    lr_gather_kernel<<<nblocks, 256, 0, stream>>>((const f32x4*)x, idx_g,
                                                  (f32x4*)out, T);
}

// Round 5
// 435.798 us; speedup vs baseline: 1.0399x; 1.0066x over previous
//
#include <hip/hip_runtime.h>

// LengthRegulator, fully fused single kernel.
// x (32,1024,384) f32, duration (32,1024) i32, T=8192.
// out0: (32, 8192, 384) f32 gathered+masked;  out1: mel_len (32,) as f32.
//
// 8192 blocks x 256 thr (XCD-swizzled). Each block:
//  1. int4-loads its batch's duration (4 KB, L2-broadcast across blocks),
//     computes the full inclusive csum in-register: thread-local sum-of-4 +
//     wave shuffle-scan + 4 wave totals in LDS (2 barriers, ~0.5 us).
//  2. Run-intersection scatter: thread's 4 runs [start,end) intersected with
//     the block's output-row window [t0, t0+32) -> src[] in LDS (-1 = masked).
//  3. Streaming gather: 16B x-loads (L2-resident), non-temporal 16B stores.

#define BATCH 32
#define SRC_S 1024
#define DIM   384
#define ROWS  32          // output rows per block
#define C4    (DIM / 4)   // 96 16B-vectors per row
#define NXCD  8

typedef float f32x4 __attribute__((ext_vector_type(4)));
typedef int   i32x4 __attribute__((ext_vector_type(4)));

__global__ __launch_bounds__(256)
void lr_fused_kernel(const f32x4* __restrict__ x4,
                     const int* __restrict__ duration,
                     f32x4* __restrict__ out4,
                     float* __restrict__ mel_out, int T) {
    __shared__ int wsum[4];
    __shared__ int src[ROWS];

    // XCD-aware swizzle: 4 whole batches per XCD -> x working set ~6MB/XCD.
    const int l = blockIdx.x;              // 0 .. 8191
    const int xcd = l & (NXCD - 1);
    const int j = l >> 3;                  // 0 .. 1023
    const int b = xcd + NXCD * (j >> 8);   // 0 .. 31
    const int t0 = (j & 255) * ROWS;       // 0 .. 8160
    const int tid = threadIdx.x;
    const int lane = tid & 63;
    const int wid = tid >> 6;              // 4 waves

    if (tid < ROWS) src[tid] = -1;         // default: masked (zero) row

    // ---- per-block csum of duration[b,:] ----
    const i32x4 d = ((const i32x4*)(duration + b * SRC_S))[tid];
    const int s0 = d.x;
    const int s1 = s0 + d.y;
    const int s2 = s1 + d.z;
    const int s3 = s2 + d.w;               // thread-local inclusive sums
    int tot = s3;
    #pragma unroll
    for (int off = 1; off < 64; off <<= 1) {   // wave inclusive scan
        const int n = __shfl_up(tot, off, 64);
        if (lane >= off) tot += n;
    }
    if (lane == 63) wsum[wid] = tot;
    __syncthreads();
    int base = 0;                          // sum of previous waves' totals
    #pragma unroll
    for (int w = 0; w < 3; ++w) base += (w < wid) ? wsum[w] : 0;
    const int mel_len = wsum[0] + wsum[1] + wsum[2] + wsum[3];
    const int pre = base + tot - s3;       // thread's exclusive prefix

    // ---- run-intersection scatter into src[] ----
    const int cs[4] = {pre + s0, pre + s1, pre + s2, pre + s3};  // run ends
    const int st[4] = {pre, pre + s0, pre + s1, pre + s2};       // run starts
    #pragma unroll
    for (int e = 0; e < 4; ++e) {
        const int lo = (st[e] > t0) ? st[e] : t0;
        const int hi = (cs[e] < t0 + ROWS) ? cs[e] : (t0 + ROWS);
        for (int t = lo; t < hi; ++t) src[t - t0] = tid * 4 + e;
    }
    __syncthreads();

    if (t0 == 0 && tid == 0) mel_out[b] = (float)mel_len;  // exact in f32

    // ---- streaming gather ----
    const f32x4* __restrict__ xb = x4 + (size_t)b * SRC_S * C4;
    f32x4* __restrict__ ob = out4 + ((size_t)b * T + t0) * C4;

    #pragma unroll
    for (int k = 0; k < (ROWS * C4) / 256; ++k) {   // 12 iterations
        const int i = tid + k * 256;
        const int row = i / C4;                      // const-div -> magic mul
        const int col = i - row * C4;
        const int sidx = src[row];                   // LDS broadcast
        f32x4 v = (f32x4)(0.f);
        if (sidx >= 0) v = xb[(size_t)sidx * C4 + col];
        __builtin_nontemporal_store(v, &ob[i]);      // streaming out
    }
}

extern "C" void kernel_launch(void* const* d_in, const int* in_sizes, int n_in,
                              void* d_out, int out_size, void* d_ws, size_t ws_size,
                              hipStream_t stream) {
    const float* x = (const float*)d_in[0];
    const int* duration = (const int*)d_in[1];
    const int T = (out_size - BATCH) / (BATCH * DIM);   // 8192

    float* out = (float*)d_out;
    float* mel_out = out + (size_t)BATCH * T * DIM;     // out1 region

    const int nblocks = BATCH * (T / ROWS);             // 8192
    lr_fused_kernel<<<nblocks, 256, 0, stream>>>((const f32x4*)x, duration,
                                                 (f32x4*)out, mel_out, T);
}